// Round 12
// baseline (261.987 us; speedup 1.0000x reference)
//
#include <hip/hip_runtime.h>
#include <math.h>

// Chained bilinear lookup: out = bilinear(grid0, bilinear(grid1, x)),
// sigmoid per corner sample (both stages).
//
// Shapes: x (N,2) f32; grid1 (U1,U1,2) f32, U1=2080; grid0 (U0,U0,3) f32,
// U0=520; out (N,3) f32.
//
// PRECISION CONTRACT (R0-R11, passing at absmax 3.9e-3 / thr 1.96e-2):
//  - Ref is a faithful per-op float32 numpy pipeline; stage-1 output is
//    multiplied by 520 in stage 2 (errors amplified ~520x).
//  - su = x*U must be a SINGLE f32 rounded mul (inline-asm v_mul_f32 —
//    default ffp-contract=fast otherwise fuses su-floor into fma => 0.04).
//  - Sigmoid: expf (1 ulp) + f64 divide, rounded once to f32.
//  - f32 blends as written (R5/R8/R11-validated).
//
// PERF MODEL (R5-R11 ledger):
//  - Fixed ~95us harness reset traffic (untouchable) + pack ~37us
//    (173MB memory-bound) + query.
//  - Query is outstanding-line-limited: R11 1 line-chain/thread ->
//    34K lines/us; R5 with 4 chains/pt -> 47K/us. R9's 2pt/thread
//    serialized (VGPR 20). R12 (this): 2 pts/thread, all 4 cell loads
//    issued then __builtin_amdgcn_sched_barrier(0) so the compiler
//    CANNOT sink the second point's loads past the first point's
//    compute -> 2 independent 64B lines in flight per thread.

typedef float f32x2 __attribute__((ext_vector_type(2)));
typedef float f32x4 __attribute__((ext_vector_type(4)));

__device__ __forceinline__ float mul_rn_nocontract(float a, float b) {
    float r;
    asm("v_mul_f32 %0, %1, %2" : "=v"(r) : "v"(a), "v"(b));
    return r;
}

// ~1-ulp sigmoid matching numpy's f32 chain: e rounded to f32, then a
// single correctly-rounded divide done in f64 (immune to rcp lowering).
__device__ __forceinline__ float sigmoid_ref(float t) {
    float e = expf(-t);
    return (float)(1.0 / (1.0 + (double)e));
}

// ---- Phase A1: LDS-tiled corner-pack of grid1 ----
// 16x16 cells per workgroup; 17x17 corner points sigmoided once into LDS,
// then each thread assembles its cell's 8 packed floats:
//   cell (u,v) -> [s(t00).xy s(t01).xy | s(t10).xy s(t11).xy]
__global__ void __launch_bounds__(256) pack_tiled_kernel(
    const float* __restrict__ g1, float* __restrict__ pk,
    int U1, int tiles_per_row)
{
    __shared__ float sx[17][17];
    __shared__ float sy[17][17];

    int tile = blockIdx.x;
    int tu = tile / tiles_per_row;
    int tv = tile - tu * tiles_per_row;
    int ubase = tu * 16, vbase = tv * 16;

    const float2* g = reinterpret_cast<const float2*>(g1);
    for (int idx = threadIdx.x; idx < 17 * 17; idx += 256) {
        int du = idx / 17, dv = idx - du * 17;
        int u = ubase + du; if (u >= U1) u -= U1;   // wrap (ubase < U1)
        int v = vbase + dv; if (v >= U1) v -= U1;
        float2 t = g[(size_t)u * U1 + v];
        sx[du][dv] = sigmoid_ref(t.x);
        sy[du][dv] = sigmoid_ref(t.y);
    }
    __syncthreads();

    int lu = threadIdx.x >> 4, lv = threadIdx.x & 15;
    int u = ubase + lu, v = vbase + lv;
    if (u >= U1 || v >= U1) return;                 // ragged edge guard
    float4 lo = make_float4(sx[lu][lv],     sy[lu][lv],
                            sx[lu][lv + 1], sy[lu][lv + 1]);
    float4 hi = make_float4(sx[lu + 1][lv],     sy[lu + 1][lv],
                            sx[lu + 1][lv + 1], sy[lu + 1][lv + 1]);
    float4* o = reinterpret_cast<float4*>(pk + ((size_t)u * U1 + v) * 8);
    o[0] = lo;
    o[1] = hi;
}

// ---- Phase A2: elementwise sigmoid of a table (float4-vectorized) ----
__global__ void __launch_bounds__(256) sigmoid_table_kernel(
    const float4* __restrict__ in, float4* __restrict__ out, int n4)
{
    int i = blockIdx.x * blockDim.x + threadIdx.x;
    if (i >= n4) return;
    float4 v = in[i];
    float4 r;
    r.x = sigmoid_ref(v.x);
    r.y = sigmoid_ref(v.y);
    r.z = sigmoid_ref(v.z);
    r.w = sigmoid_ref(v.w);
    out[i] = r;
}

// ---- Phase B: 2 pts/thread, forced-parallel cell loads ----
__global__ void __launch_bounds__(256) query2mlp_kernel(
    const float* __restrict__ x,
    const float* __restrict__ pk,   // packed corners, U1*U1*8 floats
    const float* __restrict__ s0,   // sigmoid(grid0), (U0,U0,3), L2-resident
    float* __restrict__ out,        // (N,3)
    int N, int U1, int U0)
{
    int t = blockIdx.x * blockDim.x + threadIdx.x;
    int i0 = t * 2;
    if (i0 >= N) return;
    bool two = (i0 + 1 < N);

    f32x4 xv;
    if (two) {
        xv = __builtin_nontemporal_load(reinterpret_cast<const f32x4*>(x) + t);
    } else {
        f32x2 h = reinterpret_cast<const f32x2*>(x)[i0];
        xv.x = h.x; xv.y = h.y; xv.z = h.x; xv.w = h.y;   // duplicate pt0
    }

    // ---- stage-1 coords for both points (contract-proof muls) ----
    float fU1 = (float)U1;
    float su0 = mul_rn_nocontract(xv.x, fU1);
    float sv0 = mul_rn_nocontract(xv.y, fU1);
    float su1 = mul_rn_nocontract(xv.z, fU1);
    float sv1 = mul_rn_nocontract(xv.w, fU1);
    float u0f0 = floorf(su0), v0f0 = floorf(sv0);
    float u0f1 = floorf(su1), v0f1 = floorf(sv1);
    float fu0 = su0 - u0f0, fv0 = sv0 - v0f0;   // exact
    float fu1 = su1 - u0f1, fv1 = sv1 - v0f1;
    int ua = (int)u0f0 % U1; if (ua < 0) ua += U1;
    int va = (int)v0f0 % U1; if (va < 0) va += U1;
    int ub = (int)u0f1 % U1; if (ub < 0) ub += U1;
    int vb = (int)v0f1 % U1; if (vb < 0) vb += U1;

    // ---- issue ALL FOUR cell loads (2 independent 64B lines) ----
    const f32x4* pkv = reinterpret_cast<const f32x4*>(pk);
    size_t c0 = (size_t)(ua * U1 + va) * 2;
    size_t c1 = (size_t)(ub * U1 + vb) * 2;
    f32x4 lo0 = pkv[c0];
    f32x4 hi0 = pkv[c0 + 1];
    f32x4 lo1 = pkv[c1];
    f32x4 hi1 = pkv[c1 + 1];
    __builtin_amdgcn_sched_barrier(0);   // nothing crosses: both lines in flight

    // ---- stage-1 blends ----
    float omfu0 = 1.0f - fu0, omfv0 = 1.0f - fv0;
    float omfu1 = 1.0f - fu1, omfv1 = 1.0f - fv1;
    float kx0 = (lo0.x * omfu0 + hi0.x * fu0) * omfv0
              + (lo0.z * omfu0 + hi0.z * fu0) * fv0;
    float ky0 = (lo0.y * omfu0 + hi0.y * fu0) * omfv0
              + (lo0.w * omfu0 + hi0.w * fu0) * fv0;
    float kx1 = (lo1.x * omfu1 + hi1.x * fu1) * omfv1
              + (lo1.z * omfu1 + hi1.z * fu1) * fv1;
    float ky1 = (lo1.y * omfu1 + hi1.y * fu1) * omfv1
              + (lo1.w * omfu1 + hi1.w * fu1) * fv1;

    // ---- stage 2 for both points (L2-resident AoS table) ----
    float fU0 = (float)U0;
    float kx[2] = {kx0, kx1};
    float ky[2] = {ky0, ky1};
    float res[6];
#pragma unroll
    for (int p = 0; p < 2; ++p) {
        float su2 = mul_rn_nocontract(kx[p], fU0);
        float sv2 = mul_rn_nocontract(ky[p], fU0);
        float u0f2 = floorf(su2), v0f2 = floorf(sv2);
        float fu2 = su2 - u0f2, fv2 = sv2 - v0f2;
        int p0 = (int)u0f2 % U0; if (p0 < 0) p0 += U0;
        int q0 = (int)v0f2 % U0; if (q0 < 0) q0 += U0;
        int p1 = p0 + 1; if (p1 >= U0) p1 = 0;
        int q1 = q0 + 1; if (q1 >= U0) q1 = 0;
        int b00 = (p0 * U0 + q0) * 3, b10 = (p1 * U0 + q0) * 3;
        int b01 = (p0 * U0 + q1) * 3, b11 = (p1 * U0 + q1) * 3;
        float omfu2 = 1.0f - fu2, omfv2 = 1.0f - fv2;
        res[3*p+0] = (s0[b00+0] * omfu2 + s0[b10+0] * fu2) * omfv2
                   + (s0[b01+0] * omfu2 + s0[b11+0] * fu2) * fv2;
        res[3*p+1] = (s0[b00+1] * omfu2 + s0[b10+1] * fu2) * omfv2
                   + (s0[b01+1] * omfu2 + s0[b11+1] * fu2) * fv2;
        res[3*p+2] = (s0[b00+2] * omfu2 + s0[b10+2] * fu2) * omfv2
                   + (s0[b01+2] * omfu2 + s0[b11+2] * fu2) * fv2;
    }

    float* op = out + (size_t)i0 * 3;     // 8B-aligned (i0 even)
    if (two) {
        f32x2 o0 = {res[0], res[1]};
        f32x2 o1 = {res[2], res[3]};
        f32x2 o2 = {res[4], res[5]};
        __builtin_nontemporal_store(o0, reinterpret_cast<f32x2*>(op));
        __builtin_nontemporal_store(o1, reinterpret_cast<f32x2*>(op + 2));
        __builtin_nontemporal_store(o2, reinterpret_cast<f32x2*>(op + 4));
    } else {
        op[0] = res[0]; op[1] = res[1]; op[2] = res[2];
    }
}

// ---- Middle variant: R5's known-good unpadded query kernel ----
__global__ void __launch_bounds__(256) query_kernel_unpadded(
    const float* __restrict__ x,
    const float* __restrict__ s1,
    const float* __restrict__ s0,
    float* __restrict__ out,
    int N, int U1, int U0)
{
    int i = blockIdx.x * blockDim.x + threadIdx.x;
    if (i >= N) return;
    float2 uv = reinterpret_cast<const float2*>(x)[i];
    float fU1 = (float)U1;
    float su = mul_rn_nocontract(uv.x, fU1);
    float sv = mul_rn_nocontract(uv.y, fU1);
    float u0f = floorf(su), v0f = floorf(sv);
    float fu = su - u0f, fv = sv - v0f;
    int u0 = (int)u0f % U1; if (u0 < 0) u0 += U1;
    int v0 = (int)v0f % U1; if (v0 < 0) v0 += U1;
    int u1 = u0 + 1; if (u1 >= U1) u1 = 0;
    int v1 = v0 + 1; if (v1 >= U1) v1 = 0;
    const float2* s1v = reinterpret_cast<const float2*>(s1);
    float2 t00 = s1v[u0 * U1 + v0];
    float2 t10 = s1v[u1 * U1 + v0];
    float2 t01 = s1v[u0 * U1 + v1];
    float2 t11 = s1v[u1 * U1 + v1];
    float omfu = 1.0f - fu, omfv = 1.0f - fv;
    float kx = (t00.x * omfu + t10.x * fu) * omfv + (t01.x * omfu + t11.x * fu) * fv;
    float ky = (t00.y * omfu + t10.y * fu) * omfv + (t01.y * omfu + t11.y * fu) * fv;
    float fU0 = (float)U0;
    float su2 = mul_rn_nocontract(kx, fU0);
    float sv2 = mul_rn_nocontract(ky, fU0);
    float u0f2 = floorf(su2), v0f2 = floorf(sv2);
    float fu2 = su2 - u0f2, fv2 = sv2 - v0f2;
    int p0 = (int)u0f2 % U0; if (p0 < 0) p0 += U0;
    int q0 = (int)v0f2 % U0; if (q0 < 0) q0 += U0;
    int p1 = p0 + 1; if (p1 >= U0) p1 = 0;
    int q1 = q0 + 1; if (q1 >= U0) q1 = 0;
    int b00 = (p0 * U0 + q0) * 3, b10 = (p1 * U0 + q0) * 3;
    int b01 = (p0 * U0 + q1) * 3, b11 = (p1 * U0 + q1) * 3;
    float omfu2 = 1.0f - fu2, omfv2 = 1.0f - fv2;
    float r0 = (s0[b00+0] * omfu2 + s0[b10+0] * fu2) * omfv2
             + (s0[b01+0] * omfu2 + s0[b11+0] * fu2) * fv2;
    float r1 = (s0[b00+1] * omfu2 + s0[b10+1] * fu2) * omfv2
             + (s0[b01+1] * omfu2 + s0[b11+1] * fu2) * fv2;
    float r2 = (s0[b00+2] * omfu2 + s0[b10+2] * fu2) * omfv2
             + (s0[b01+2] * omfu2 + s0[b11+2] * fu2) * fv2;
    out[3*i+0] = r0; out[3*i+1] = r1; out[3*i+2] = r2;
}

// ---- Full fallback: all sigmoids in-kernel (ws too small) ----
__global__ void __launch_bounds__(256) query_kernel_fallback(
    const float* __restrict__ x,
    const float* __restrict__ g1,
    const float* __restrict__ g0,
    float* __restrict__ out,
    int N, int U1, int U0)
{
    int i = blockIdx.x * blockDim.x + threadIdx.x;
    if (i >= N) return;
    float2 uv = reinterpret_cast<const float2*>(x)[i];
    float fU1 = (float)U1;
    float su = mul_rn_nocontract(uv.x, fU1);
    float sv = mul_rn_nocontract(uv.y, fU1);
    float u0f = floorf(su), v0f = floorf(sv);
    float fu = su - u0f, fv = sv - v0f;
    int u0 = (int)u0f % U1; if (u0 < 0) u0 += U1;
    int v0 = (int)v0f % U1; if (v0 < 0) v0 += U1;
    int u1 = u0 + 1; if (u1 >= U1) u1 = 0;
    int v1 = v0 + 1; if (v1 >= U1) v1 = 0;
    const float2* g1v = reinterpret_cast<const float2*>(g1);
    float2 t00 = g1v[u0 * U1 + v0];
    float2 t10 = g1v[u1 * U1 + v0];
    float2 t01 = g1v[u0 * U1 + v1];
    float2 t11 = g1v[u1 * U1 + v1];
    float a00x = sigmoid_ref(t00.x), a00y = sigmoid_ref(t00.y);
    float a10x = sigmoid_ref(t10.x), a10y = sigmoid_ref(t10.y);
    float a01x = sigmoid_ref(t01.x), a01y = sigmoid_ref(t01.y);
    float a11x = sigmoid_ref(t11.x), a11y = sigmoid_ref(t11.y);
    float omfu = 1.0f - fu, omfv = 1.0f - fv;
    float kx = (a00x * omfu + a10x * fu) * omfv + (a01x * omfu + a11x * fu) * fv;
    float ky = (a00y * omfu + a10y * fu) * omfv + (a01y * omfu + a11y * fu) * fv;
    float fU0 = (float)U0;
    float su2 = mul_rn_nocontract(kx, fU0);
    float sv2 = mul_rn_nocontract(ky, fU0);
    float u0f2 = floorf(su2), v0f2 = floorf(sv2);
    float fu2 = su2 - u0f2, fv2 = sv2 - v0f2;
    int p0 = (int)u0f2 % U0; if (p0 < 0) p0 += U0;
    int q0 = (int)v0f2 % U0; if (q0 < 0) q0 += U0;
    int p1 = p0 + 1; if (p1 >= U0) p1 = 0;
    int q1 = q0 + 1; if (q1 >= U0) q1 = 0;
    int b00 = (p0 * U0 + q0) * 3, b10 = (p1 * U0 + q0) * 3;
    int b01 = (p0 * U0 + q1) * 3, b11 = (p1 * U0 + q1) * 3;
    float omfu2 = 1.0f - fu2, omfv2 = 1.0f - fv2;
    float r0 = (sigmoid_ref(g0[b00+0]) * omfu2 + sigmoid_ref(g0[b10+0]) * fu2) * omfv2
             + (sigmoid_ref(g0[b01+0]) * omfu2 + sigmoid_ref(g0[b11+0]) * fu2) * fv2;
    float r1 = (sigmoid_ref(g0[b00+1]) * omfu2 + sigmoid_ref(g0[b10+1]) * fu2) * omfv2
             + (sigmoid_ref(g0[b01+1]) * omfu2 + sigmoid_ref(g0[b11+1]) * fu2) * fv2;
    float r2 = (sigmoid_ref(g0[b00+2]) * omfu2 + sigmoid_ref(g0[b10+2]) * fu2) * omfv2
             + (sigmoid_ref(g0[b01+2]) * omfu2 + sigmoid_ref(g0[b11+2]) * fu2) * fv2;
    out[3*i+0] = r0; out[3*i+1] = r1; out[3*i+2] = r2;
}

extern "C" void kernel_launch(void* const* d_in, const int* in_sizes, int n_in,
                              void* d_out, int out_size, void* d_ws, size_t ws_size,
                              hipStream_t stream) {
    const float* x  = (const float*)d_in[0];
    const float* g1 = (const float*)d_in[1];
    const float* g0 = (const float*)d_in[2];
    float* out = (float*)d_out;

    int N = in_sizes[0] / 2;
    long long n1 = in_sizes[1];          // U1*U1*2
    long long n0 = in_sizes[2];          // U0*U0*3
    int U1 = (int)(sqrt((double)(n1 / 2)) + 0.5);
    int U0 = (int)(sqrt((double)(n0 / 3)) + 0.5);
    long long ncells1 = (long long)U1 * U1;

    int block = 256;
    size_t need_packed = ((size_t)ncells1 * 8 + (size_t)n0) * sizeof(float);
    size_t need_plain  = ((size_t)n1 + (size_t)n0) * sizeof(float);

    if (ws_size >= need_packed && (n0 % 4) == 0) {
        float* pk = (float*)d_ws;                     // 138.4 MB packed
        float* s0 = pk + ncells1 * 8;                 // 3.2 MB sigmoided g0
        int n0_4 = (int)(n0 / 4);
        int tiles_per_row = (U1 + 15) / 16;
        int ntiles = tiles_per_row * tiles_per_row;
        pack_tiled_kernel<<<ntiles, block, 0, stream>>>(g1, pk, U1, tiles_per_row);
        sigmoid_table_kernel<<<(n0_4 + block - 1) / block, block, 0, stream>>>(
            (const float4*)g0, (float4*)s0, n0_4);
        int nthreads = (N + 1) / 2;
        query2mlp_kernel<<<(nthreads + block - 1) / block, block, 0, stream>>>(
            x, pk, s0, out, N, U1, U0);
    } else if (ws_size >= need_plain && (n1 % 4) == 0 && (n0 % 4) == 0) {
        float* s1 = (float*)d_ws;
        float* s0 = s1 + n1;
        int n1_4 = (int)(n1 / 4), n0_4 = (int)(n0 / 4);
        sigmoid_table_kernel<<<(n1_4 + block - 1) / block, block, 0, stream>>>(
            (const float4*)g1, (float4*)s1, n1_4);
        sigmoid_table_kernel<<<(n0_4 + block - 1) / block, block, 0, stream>>>(
            (const float4*)g0, (float4*)s0, n0_4);
        query_kernel_unpadded<<<(N + block - 1) / block, block, 0, stream>>>(
            x, s1, s0, out, N, U1, U0);
    } else {
        query_kernel_fallback<<<(N + block - 1) / block, block, 0, stream>>>(
            x, g1, g0, out, N, U1, U0);
    }
}